// Round 1
// baseline (1198.788 us; speedup 1.0000x reference)
//
#include <hip/hip_runtime.h>
#include <hip/hip_bf16.h>

// QuantizedLinear: fp8-e4m3 fake-quant (dynamic per-tensor scale) of x and W,
// then out = qx @ qW^T + bias.
//
// Pipeline (all on `stream`):
//   1. memset ws[0:256) = 0                      (amax slots)
//   2. amax_kernel(x) -> ws[0], amax_kernel(w) -> ws[1]   (atomicMax on bits)
//   3. quant_kernel: xs = clamp(x*448/amax, +-448), RNE-round mantissa to 3
//      bits (bit trick == round(xs/lsb)*lsb of the reference), store SCALED
//      value as bf16 (exact: <=4 mantissa bits). Dequant deferred to epilogue.
//   4. gemm: 128x128 tile, BK=64, 4 waves (2x2), mfma_f32_16x16x32_bf16,
//      global_load_lds width 16, epilogue: acc * (amax_x*amax_w/448^2) + bias.

typedef __attribute__((ext_vector_type(8))) __bf16 bf16x8;
typedef __attribute__((ext_vector_type(4))) float f32x4;
typedef __attribute__((ext_vector_type(4))) unsigned int u32x4;

#define FP8_MAX 448.0f
#define TINY 5.9604644775390625e-8f   // 2^-24

__device__ __forceinline__ void gload_lds16(const void* g, void* l) {
  __builtin_amdgcn_global_load_lds(
      (__attribute__((address_space(1))) void*)g,
      (__attribute__((address_space(3))) void*)l, 16, 0, 0);
}

// ---------------- amax ----------------
__global__ __launch_bounds__(256) void amax_kernel(
    const float* __restrict__ in, long n, unsigned* __restrict__ out) {
  long i0 = (long)blockIdx.x * blockDim.x + threadIdx.x;
  long stride = (long)gridDim.x * blockDim.x;
  long n4 = n >> 2;
  const float4* in4 = (const float4*)in;
  float m = 0.f;
  for (long i = i0; i < n4; i += stride) {
    float4 v = in4[i];
    m = fmaxf(m, fmaxf(fmaxf(fabsf(v.x), fabsf(v.y)),
                       fmaxf(fabsf(v.z), fabsf(v.w))));
  }
  #pragma unroll
  for (int off = 32; off > 0; off >>= 1)
    m = fmaxf(m, __shfl_xor(m, off, 64));
  __shared__ float red[4];
  int lane = threadIdx.x & 63, wid = threadIdx.x >> 6;
  if (lane == 0) red[wid] = m;
  __syncthreads();
  if (threadIdx.x == 0) {
    m = fmaxf(fmaxf(red[0], red[1]), fmaxf(red[2], red[3]));
    atomicMax(out, __float_as_uint(m));  // positive-float bits order-preserving
  }
}

// ---------------- fake-quant to scaled bf16 ----------------
__device__ __forceinline__ unsigned short fq1(float x, float s) {
  float xs = x * s;
  xs = fminf(fmaxf(xs, -FP8_MAX), FP8_MAX);
  unsigned u = __float_as_uint(xs);
  unsigned sign = u & 0x80000000u;
  unsigned mag = u & 0x7fffffffu;
  // RNE round mantissa to 3 bits: == round(xs/lsb)*lsb, lsb=2^(floor(log2)-3)
  unsigned r = (mag + 0x7FFFFu + ((mag >> 20) & 1u)) & 0xFFF00000u;
  return (unsigned short)((sign | r) >> 16);  // exact bf16 (<=4 mantissa bits)
}

__global__ __launch_bounds__(256) void quant_kernel(
    const float* __restrict__ in, unsigned short* __restrict__ out,
    const unsigned* __restrict__ amaxp, long n) {
  float s = FP8_MAX / fmaxf(__uint_as_float(*amaxp), TINY);
  long i0 = (long)blockIdx.x * blockDim.x + threadIdx.x;
  long stride = (long)gridDim.x * blockDim.x;
  long n4 = n >> 2;
  const float4* in4 = (const float4*)in;
  uint2* out4 = (uint2*)out;
  for (long i = i0; i < n4; i += stride) {
    float4 v = in4[i];
    unsigned a = fq1(v.x, s), b = fq1(v.y, s), c = fq1(v.z, s), d = fq1(v.w, s);
    uint2 o;
    o.x = a | (b << 16);
    o.y = c | (d << 16);
    out4[i] = o;
  }
}

// ---------------- GEMM: C[t,o] = sum_k qx[t,k]*qw[o,k]; epilogue scale+bias --
__global__ __launch_bounds__(256, 2) void gemm_kernel(
    const unsigned short* __restrict__ qx, const unsigned short* __restrict__ qw,
    const float* __restrict__ bias, const unsigned* __restrict__ amaxp,
    float* __restrict__ out, int M, int N, int K) {
  __shared__ unsigned short As[128 * 64];  // [row][k], 128B rows
  __shared__ unsigned short Bs[128 * 64];
  const int tid = threadIdx.x;
  const int lane = tid & 63;
  const int wid = tid >> 6;
  const int wm = wid >> 1, wn = wid & 1;  // 2x2 wave grid, 64x64 per wave
  const int bm0 = blockIdx.y * 128;
  const int bn0 = blockIdx.x * 128;

  f32x4 acc[4][4] = {};

  const int arow = wm * 64 + (lane & 15);
  const int brow = wn * 64 + (lane & 15);
  const int koff = (lane >> 4) << 3;  // k-chunk of 8 per 16-lane group

  for (int kt = 0; kt < K; kt += 64) {
    #pragma unroll
    for (int i = 0; i < 4; ++i) {
      int off = i * 4096 + wid * 1024 + lane * 16;  // byte off in 16KB tile
      int r = off >> 7;       // row
      int c = off & 127;      // byte within row
      gload_lds16((const char*)qx + (((size_t)(bm0 + r) * K + kt) << 1) + c,
                  (char*)As + i * 4096 + wid * 1024);
      gload_lds16((const char*)qw + (((size_t)(bn0 + r) * K + kt) << 1) + c,
                  (char*)Bs + i * 4096 + wid * 1024);
    }
    __syncthreads();  // compiler drains vmcnt before s_barrier
    #pragma unroll
    for (int kk = 0; kk < 2; ++kk) {
      bf16x8 af[4], bfr[4];
      #pragma unroll
      for (int t = 0; t < 4; ++t) {
        af[t] = __builtin_bit_cast(
            bf16x8, *(const u32x4*)&As[(arow + t * 16) * 64 + kk * 32 + koff]);
        bfr[t] = __builtin_bit_cast(
            bf16x8, *(const u32x4*)&Bs[(brow + t * 16) * 64 + kk * 32 + koff]);
      }
      #pragma unroll
      for (int mt = 0; mt < 4; ++mt)
        #pragma unroll
        for (int nt = 0; nt < 4; ++nt)
          acc[mt][nt] = __builtin_amdgcn_mfma_f32_16x16x32_bf16(
              af[mt], bfr[nt], acc[mt][nt], 0, 0, 0);
    }
    __syncthreads();
  }

  // epilogue: dequant scale + bias. 1/(sx*sw) = amax_x*amax_w/448^2
  const float ax = fmaxf(__uint_as_float(amaxp[0]), TINY);
  const float aw = fmaxf(__uint_as_float(amaxp[1]), TINY);
  const float inv = ax * aw * (1.0f / (FP8_MAX * FP8_MAX));
  const int col0 = bn0 + wn * 64 + (lane & 15);
  const int row0 = bm0 + wm * 64 + ((lane >> 4) << 2);
  float bv[4];
  #pragma unroll
  for (int nt = 0; nt < 4; ++nt) bv[nt] = bias[col0 + nt * 16];
  #pragma unroll
  for (int mt = 0; mt < 4; ++mt)
    #pragma unroll
    for (int nt = 0; nt < 4; ++nt)
      #pragma unroll
      for (int j = 0; j < 4; ++j)
        out[(size_t)(row0 + mt * 16 + j) * N + col0 + nt * 16] =
            acc[mt][nt][j] * inv + bv[nt];
}

extern "C" void kernel_launch(void* const* d_in, const int* in_sizes, int n_in,
                              void* d_out, int out_size, void* d_ws, size_t ws_size,
                              hipStream_t stream) {
  const float* x = (const float*)d_in[0];
  const float* w = (const float*)d_in[1];
  const float* bias = (const float*)d_in[2];
  float* out = (float*)d_out;

  long nx = in_sizes[0];
  long nw = in_sizes[1];
  int N = in_sizes[2];          // 16384
  int K = (int)(nw / N);        // 4096
  int M = (int)(nx / K);        // 4096

  unsigned* amax = (unsigned*)d_ws;
  unsigned short* qx = (unsigned short*)((char*)d_ws + 256);
  unsigned short* qw = (unsigned short*)((char*)d_ws + 256 + (size_t)M * K * 2);

  hipMemsetAsync(d_ws, 0, 256, stream);
  amax_kernel<<<2048, 256, 0, stream>>>(x, nx, amax + 0);
  amax_kernel<<<2048, 256, 0, stream>>>(w, nw, amax + 1);
  quant_kernel<<<2048, 256, 0, stream>>>(x, qx, amax + 0, nx);
  quant_kernel<<<2048, 256, 0, stream>>>(w, qw, amax + 1, nw);

  dim3 grid(N / 128, M / 128);
  gemm_kernel<<<grid, 256, 0, stream>>>(qx, qw, bias, amax, out, M, N, K);
}